// Round 2
// baseline (680.401 us; speedup 1.0000x reference)
//
#include <hip/hip_runtime.h>

// Problem constants (from reference setup_inputs)
#define SEQ 2048
#define BATCH 64
#define DIM 1024
#define S_PER_WAVE 16

// Kernel 1: energies[b, s] = dot(hidden[b, :], enc[s, b, :])
// One wave (64 lanes) handles ONE b and 16 consecutive s values.
// hidden[b,:] is loaded into registers once (4 float4/lane); the wave then
// streams 16 enc rows (64 KiB) with 16 independent accumulators, giving the
// memory pipe 64 fully-coalesced 1 KiB loads with no cross-iteration deps.
// Wave id layout: b fastest -> 64 consecutive waves stream a contiguous
// 4 MiB slab of enc ( (s*64+b)*4KiB is sequential in w ).
__global__ __launch_bounds__(256) void energies_kernel(
    const float* __restrict__ hidden,   // [BATCH, DIM]
    const float* __restrict__ enc,      // [SEQ, BATCH, DIM]
    float* __restrict__ out)            // [BATCH, SEQ] energies (pre-softmax)
{
    const int wave = threadIdx.x >> 6;             // 0..3
    const int lane = threadIdx.x & 63;
    const int w = blockIdx.x * 4 + wave;           // 0..8191
    const int b = w & (BATCH - 1);
    const int s0 = (w >> 6) * S_PER_WAVE;          // 0,16,...,2032

    const float4* h4 = (const float4*)(hidden + (size_t)b * DIM);
    float4 h0 = h4[lane];
    float4 h1 = h4[64 + lane];
    float4 h2 = h4[128 + lane];
    float4 h3 = h4[192 + lane];

    float acc[S_PER_WAVE];
#pragma unroll
    for (int i = 0; i < S_PER_WAVE; ++i) {
        const float4* e4 =
            (const float4*)(enc + ((size_t)(s0 + i) * BATCH + b) * DIM);
        float4 e0 = e4[lane];
        float4 e1 = e4[64 + lane];
        float4 e2 = e4[128 + lane];
        float4 e3 = e4[192 + lane];
        float a;
        a  = e0.x * h0.x + e0.y * h0.y + e0.z * h0.z + e0.w * h0.w;
        a += e1.x * h1.x + e1.y * h1.y + e1.z * h1.z + e1.w * h1.w;
        a += e2.x * h2.x + e2.y * h2.y + e2.z * h2.z + e2.w * h2.w;
        a += e3.x * h3.x + e3.y * h3.y + e3.z * h3.z + e3.w * h3.w;
        acc[i] = a;
    }

    // 64-lane wave reductions; lane 0 stores each result.
    float* orow = out + (size_t)b * SEQ + s0;
#pragma unroll
    for (int i = 0; i < S_PER_WAVE; ++i) {
        float a = acc[i];
#pragma unroll
        for (int off = 32; off > 0; off >>= 1)
            a += __shfl_down(a, off, 64);
        if (lane == 0)
            orow[i] = a;
    }
}

// Kernel 2: in-place row softmax over SEQ for each b. One block per b.
__global__ __launch_bounds__(256) void softmax_kernel(float* __restrict__ out)
{
    const int b = blockIdx.x;
    float* row = out + (size_t)b * SEQ;
    const int t = threadIdx.x;
    const int lane = t & 63;
    const int wv = t >> 6;

    __shared__ float red_max[4];
    __shared__ float red_sum[4];

    float v[8];
    float m = -INFINITY;
#pragma unroll
    for (int j = 0; j < 8; ++j) {
        v[j] = row[t + j * 256];
        m = fmaxf(m, v[j]);
    }
#pragma unroll
    for (int off = 1; off < 64; off <<= 1)
        m = fmaxf(m, __shfl_xor(m, off, 64));
    if (lane == 0) red_max[wv] = m;
    __syncthreads();
    m = fmaxf(fmaxf(red_max[0], red_max[1]), fmaxf(red_max[2], red_max[3]));

    float sum = 0.f;
#pragma unroll
    for (int j = 0; j < 8; ++j) {
        v[j] = __expf(v[j] - m);
        sum += v[j];
    }
#pragma unroll
    for (int off = 1; off < 64; off <<= 1)
        sum += __shfl_xor(sum, off, 64);
    if (lane == 0) red_sum[wv] = sum;
    __syncthreads();
    sum = (red_sum[0] + red_sum[1]) + (red_sum[2] + red_sum[3]);

    const float inv = 1.0f / sum;
#pragma unroll
    for (int j = 0; j < 8; ++j)
        row[t + j * 256] = v[j] * inv;
}

extern "C" void kernel_launch(void* const* d_in, const int* in_sizes, int n_in,
                              void* d_out, int out_size, void* d_ws, size_t ws_size,
                              hipStream_t stream) {
    const float* hidden = (const float*)d_in[0];   // [1, 64, 1024]
    const float* enc    = (const float*)d_in[1];   // [2048, 64, 1024]
    float* out          = (float*)d_out;           // [64, 1, 2048]

    // 8192 waves / 4 waves-per-block = 2048 blocks (8 per CU, all resident)
    energies_kernel<<<(SEQ * BATCH) / (4 * S_PER_WAVE), 256, 0, stream>>>(
        hidden, enc, out);
    softmax_kernel<<<BATCH, 256, 0, stream>>>(out);
}